// Round 14
// baseline (417.913 us; speedup 1.0000x reference)
//
#include <hip/hip_runtime.h>
#include <math.h>

#define N_NODES 100000
#define ZERO_NODE 100000        // sentinel row (zeroed) for neighbor-list padding
#define N_EDGES 1600000
#define NBKT    391             // ceil(100000/256) coarse buckets (256 nodes each)
#define BCAP    5120            // per-bucket capacity; mean 4092, +16 sigma
#define EPB     4096            // edges per binA block (16-entry reg stash, no spill)
#define NBLKA   391             // ceil(N_EDGES/EPB)
#define PADBKT  1792            // max padding per bucket = 7*256 (pad to x8)
#define BUCKET_CAP (N_EDGES + NBKT * PADBKT + 2 * BCAP)  // + slack for clamped OOB reads

using short8  = __attribute__((ext_vector_type(8))) short;   // 8 bf16 (4 VGPRs)
using float4v = __attribute__((ext_vector_type(4))) float;   // MFMA C/D frag
using floatx2 = __attribute__((ext_vector_type(2))) float;

__device__ inline unsigned short f2bf(float f) {             // fp32 -> bf16 RNE
    unsigned int u = __float_as_uint(f);
    u += 0x7fffu + ((u >> 16) & 1u);
    return (unsigned short)(u >> 16);
}
__device__ inline float bflo(unsigned int v) { return __uint_as_float(v << 16); }
__device__ inline float bfhi(unsigned int v) { return __uint_as_float(v & 0xffff0000u); }
__device__ inline unsigned char f2fp8(float f) {             // fp32 -> fp8 e4m3 (hw)
    return (unsigned char)(__builtin_amdgcn_cvt_pk_fp8_f32(f, f, 0, false) & 0xff);
}
__device__ inline unsigned pk4fp8(float a, float b, float c, float d) {
    unsigned p = __builtin_amdgcn_cvt_pk_fp8_f32(a, b, 0, false);
    return __builtin_amdgcn_cvt_pk_fp8_f32(c, d, p, true);
}

// ---- prep: weights->bf16 [n][k]; x -> bf16 (xb) AND fp8 (xq); sentinel rows ----
__global__ void prep_all(const float* __restrict__ x, unsigned short* __restrict__ xb,
                         unsigned* __restrict__ xq,
                         const float* __restrict__ Wl1, const float* __restrict__ Wr1,
                         const float* __restrict__ Wl2, const float* __restrict__ Wr2,
                         const float* __restrict__ Wc1, const float* __restrict__ Wc2,
                         unsigned short* __restrict__ w1, unsigned short* __restrict__ w2,
                         unsigned short* __restrict__ wcls1, unsigned short* __restrict__ wcls2,
                         unsigned* __restrict__ t2q) {
    int bid = blockIdx.x;
    int t = threadIdx.x;
    if (bid < 6250) {                                  // x conversion (4 ch / thread)
        int i = bid * 256 + t;
        float4 v = *(const float4*)(x + (long)i * 4);
        uint2 o;
        o.x = (unsigned)f2bf(v.x) | ((unsigned)f2bf(v.y) << 16);
        o.y = (unsigned)f2bf(v.z) | ((unsigned)f2bf(v.w) << 16);
        *(uint2*)(xb + (long)i * 4) = o;
        xq[i] = pk4fp8(v.x, v.y, v.z, v.w);
    } else if (bid < 6442) {                           // weights
        int i = (bid - 6250) * 256 + t;
        if (i < 16384) {
            int n = i >> 7, k = i & 127;
            float v = (k < 64) ? Wl1[k * 128 + n] : Wr1[(k - 64) * 128 + n];
            w1[i] = f2bf(v);
        } else if (i < 32768) {
            int j = i - 16384; int n = j >> 7, k = j & 127;
            float v = (n < 64) ? Wl2[k * 64 + n] : Wr2[k * 64 + (n - 64)];
            w2[j] = f2bf(v);
        } else if (i < 40960) {
            int j = i - 32768; int n = j >> 6, k = j & 63;
            wcls1[j] = f2bf(Wc1[k * 128 + n]);
        } else {
            int j = i - 40960; int n = j >> 7, k = j & 127;
            wcls2[j] = f2bf(Wc2[k * 64 + n]);
        }
    } else {                                           // zero sentinel rows
        if (t < 32)       ((unsigned*)(xb + (long)ZERO_NODE * 64))[t] = 0u;
        else if (t < 48)  xq[(long)ZERO_NODE * 16 + (t - 32)] = 0u;
        else if (t < 64)  t2q[(long)ZERO_NODE * 16 + (t - 48)] = 0u;
    }
}

// ---- binned CSR build: phase A (16-entry register stash, no spill) ----
__global__ __launch_bounds__(256) void binA(const int* __restrict__ esrc,
                                            const int* __restrict__ edst,
                                            int* __restrict__ bcnt,
                                            unsigned* __restrict__ stage) {
    __shared__ int hist[NBKT];
    __shared__ int rbase[NBKT];
    int t = threadIdx.x;
    for (int i = t; i < NBKT; i += 256) hist[i] = 0;
    __syncthreads();
    int e0 = blockIdx.x * EPB;
    int e1 = e0 + EPB; if (e1 > N_EDGES) e1 = N_EDGES;
    unsigned pk[16];
    int bn[16];
#pragma unroll
    for (int j = 0; j < 16; j++) {
        int e = e0 + j * 256 + t;
        bn[j] = -1;
        if (e < N_EDGES && e < e1) {
            int d = edst[e];
            int s = esrc[e];
            int b = d >> 8;
            pk[j] = (unsigned)s | ((unsigned)(d & 255) << 24);
            bn[j] = b;
            atomicAdd(&hist[b], 1);
        }
    }
    __syncthreads();
    for (int i = t; i < NBKT; i += 256) {
        int c = hist[i];
        rbase[i] = c ? atomicAdd(&bcnt[i], c) : 0;
        hist[i] = 0;
    }
    __syncthreads();
#pragma unroll
    for (int j = 0; j < 16; j++) {
        if (bn[j] >= 0) {
            int b = bn[j];
            int slot = rbase[b] + atomicAdd(&hist[b], 1);
            if (slot < BCAP)
                stage[(long)b * BCAP + slot] = pk[j];
        }
    }
}

// Phase B: one block per bucket; self-scans bcnt; pad each node's list to x8.
__global__ __launch_bounds__(256) void binB(const int* __restrict__ bcnt,
                                            const unsigned* __restrict__ stage,
                                            int* __restrict__ offp, int* __restrict__ deg,
                                            int* __restrict__ bucket) {
    __shared__ int sg[512];
    __shared__ int hist[256];
    __shared__ int scn[256];
    __shared__ int lbase[256];
    int b = blockIdx.x, t = threadIdx.x;
    sg[t]       = (t < NBKT) ? bcnt[t] : 0;
    sg[t + 256] = (t + 256 < NBKT) ? bcnt[t + 256] : 0;
    hist[t] = 0;
    __syncthreads();
    for (int st = 1; st < 512; st <<= 1) {
        int a0 = (t >= st) ? sg[t - st] : 0;
        int a1 = (t + 256 >= st) ? sg[t + 256 - st] : 0;
        __syncthreads();
        sg[t] += a0; sg[t + 256] += a1;
        __syncthreads();
    }
    int cntraw = bcnt[b];
    int base = (sg[b] - cntraw) + b * PADBKT;
    int cnt = cntraw > BCAP ? BCAP : cntraw;
    const unsigned* sp = stage + (long)b * BCAP;
    unsigned pk[20];
    int nv = 0;
#pragma unroll
    for (int j = 0; j < 20; j++) {
        int i = j * 256 + t;
        if (i < cnt) {
            pk[j] = sp[i];
            atomicAdd(&hist[pk[j] >> 24], 1);
            nv = j + 1;
        }
    }
    __syncthreads();
    int v = hist[t];                       // true degree
    int p8 = (v + 7) & ~7;                 // padded x8
    scn[t] = p8;
    __syncthreads();
    for (int st = 1; st < 256; st <<= 1) {
        int a = (t >= st) ? scn[t - st] : 0;
        __syncthreads();
        scn[t] += a;
        __syncthreads();
    }
    lbase[t] = scn[t] - p8;
    int node = b * 256 + t;
    if (node < N_NODES) {
        offp[node] = base + lbase[t];
        deg[node]  = v;
    }
    hist[t] = 0;
    __syncthreads();
#pragma unroll
    for (int j = 0; j < 20; j++) {
        if (j < nv) {
            unsigned p = pk[j];
            int ln = p >> 24;
            int slot = atomicAdd(&hist[ln], 1);
            bucket[base + lbase[ln] + slot] = (int)(p & 0xFFFFFFu);
        }
    }
    int ps = base + lbase[t] + v;
    int pe = base + lbase[t] + p8;
    for (int j = ps; j < pe; j++) bucket[j] = ZERO_NODE;   // <=7 iters
}

// ---- fp8 gather: 2 nodes/wave. lane = (nh, slot g in [0,8), row-quarter c16 in [0,4)) ----
// fp8 row = 64 B; each lane loads 16 B (16 channels); hw cvt decode; fp32 accumulate.
__global__ __launch_bounds__(256, 8) void gather_b(
        const unsigned char* __restrict__ yq, const int* __restrict__ offp,
        const int* __restrict__ deg, const int* __restrict__ bucket,
        unsigned short* __restrict__ outb) {
    int t = threadIdx.x;
    int wv = t >> 6, lane = t & 63;
    int nh = lane >> 5;
    int g  = (lane >> 2) & 7;
    int c16 = lane & 3;
    int node = blockIdx.x * 8 + wv * 2 + nh;       // 12500*8 = 100000 exact
    int e0 = offp[node];
    int dg = deg[node];
    int len = (dg + 7) & ~7;
    int other = __shfl_xor(len, 32);
    int maxlen = len > other ? len : other;
    float a[16];
#pragma unroll
    for (int j = 0; j < 16; j++) a[j] = 0.f;
    for (int base = 0; base < maxlen; base += 32) {
        uint4 v[4];
#pragma unroll
        for (int h = 0; h < 4; h++) {
            int rel = base + h * 8 + g;
            int s = bucket[e0 + rel];
            s = (rel < len) ? s : ZERO_NODE;       // clamp BEFORE row load
            unsigned off = ((unsigned)s << 6) + ((unsigned)c16 << 4);
            v[h] = *(const uint4*)(yq + off);
        }
#pragma unroll
        for (int h = 0; h < 4; h++) {
            floatx2 d;
            d = __builtin_amdgcn_cvt_pk_f32_fp8(v[h].x, false); a[0] += d.x;  a[1] += d.y;
            d = __builtin_amdgcn_cvt_pk_f32_fp8(v[h].x, true);  a[2] += d.x;  a[3] += d.y;
            d = __builtin_amdgcn_cvt_pk_f32_fp8(v[h].y, false); a[4] += d.x;  a[5] += d.y;
            d = __builtin_amdgcn_cvt_pk_f32_fp8(v[h].y, true);  a[6] += d.x;  a[7] += d.y;
            d = __builtin_amdgcn_cvt_pk_f32_fp8(v[h].z, false); a[8] += d.x;  a[9] += d.y;
            d = __builtin_amdgcn_cvt_pk_f32_fp8(v[h].z, true);  a[10] += d.x; a[11] += d.y;
            d = __builtin_amdgcn_cvt_pk_f32_fp8(v[h].w, false); a[12] += d.x; a[13] += d.y;
            d = __builtin_amdgcn_cvt_pk_f32_fp8(v[h].w, true);  a[14] += d.x; a[15] += d.y;
        }
    }
#pragma unroll
    for (int j = 0; j < 16; j++) {                 // reduce over g (lane bits 2,3,4)
        a[j] += __shfl_xor(a[j], 4);
        a[j] += __shfl_xor(a[j], 8);
        a[j] += __shfl_xor(a[j], 16);
    }
    if (g == 0) {                                  // 4 lanes/node, 16 bf16 ch each
        float sc = 1.f / fmaxf((float)dg, 1.f);
        uint4 o0, o1;
        o0.x = (unsigned)f2bf(a[0]*sc)  | ((unsigned)f2bf(a[1]*sc) << 16);
        o0.y = (unsigned)f2bf(a[2]*sc)  | ((unsigned)f2bf(a[3]*sc) << 16);
        o0.z = (unsigned)f2bf(a[4]*sc)  | ((unsigned)f2bf(a[5]*sc) << 16);
        o0.w = (unsigned)f2bf(a[6]*sc)  | ((unsigned)f2bf(a[7]*sc) << 16);
        o1.x = (unsigned)f2bf(a[8]*sc)  | ((unsigned)f2bf(a[9]*sc) << 16);
        o1.y = (unsigned)f2bf(a[10]*sc) | ((unsigned)f2bf(a[11]*sc) << 16);
        o1.z = (unsigned)f2bf(a[12]*sc) | ((unsigned)f2bf(a[13]*sc) << 16);
        o1.w = (unsigned)f2bf(a[14]*sc) | ((unsigned)f2bf(a[15]*sc) << 16);
        unsigned short* op = outb + (long)node * 64 + c16 * 16;
        *(uint4*)op = o0;
        *(uint4*)(op + 8) = o1;
    }
}

__global__ __launch_bounds__(256, 8) void gather_badd(
        const unsigned char* __restrict__ yq, const int* __restrict__ offp,
        const int* __restrict__ deg, const int* __restrict__ bucket,
        const unsigned short* __restrict__ ub, float* __restrict__ out) {
    int t = threadIdx.x;
    int wv = t >> 6, lane = t & 63;
    int nh = lane >> 5;
    int g  = (lane >> 2) & 7;
    int c16 = lane & 3;
    int node = blockIdx.x * 8 + wv * 2 + nh;
    int e0 = offp[node];
    int dg = deg[node];
    int len = (dg + 7) & ~7;
    int other = __shfl_xor(len, 32);
    int maxlen = len > other ? len : other;
    float a[16];
#pragma unroll
    for (int j = 0; j < 16; j++) a[j] = 0.f;
    for (int base = 0; base < maxlen; base += 32) {
        uint4 v[4];
#pragma unroll
        for (int h = 0; h < 4; h++) {
            int rel = base + h * 8 + g;
            int s = bucket[e0 + rel];
            s = (rel < len) ? s : ZERO_NODE;
            unsigned off = ((unsigned)s << 6) + ((unsigned)c16 << 4);
            v[h] = *(const uint4*)(yq + off);
        }
#pragma unroll
        for (int h = 0; h < 4; h++) {
            floatx2 d;
            d = __builtin_amdgcn_cvt_pk_f32_fp8(v[h].x, false); a[0] += d.x;  a[1] += d.y;
            d = __builtin_amdgcn_cvt_pk_f32_fp8(v[h].x, true);  a[2] += d.x;  a[3] += d.y;
            d = __builtin_amdgcn_cvt_pk_f32_fp8(v[h].y, false); a[4] += d.x;  a[5] += d.y;
            d = __builtin_amdgcn_cvt_pk_f32_fp8(v[h].y, true);  a[6] += d.x;  a[7] += d.y;
            d = __builtin_amdgcn_cvt_pk_f32_fp8(v[h].z, false); a[8] += d.x;  a[9] += d.y;
            d = __builtin_amdgcn_cvt_pk_f32_fp8(v[h].z, true);  a[10] += d.x; a[11] += d.y;
            d = __builtin_amdgcn_cvt_pk_f32_fp8(v[h].w, false); a[12] += d.x; a[13] += d.y;
            d = __builtin_amdgcn_cvt_pk_f32_fp8(v[h].w, true);  a[14] += d.x; a[15] += d.y;
        }
    }
#pragma unroll
    for (int j = 0; j < 16; j++) {
        a[j] += __shfl_xor(a[j], 4);
        a[j] += __shfl_xor(a[j], 8);
        a[j] += __shfl_xor(a[j], 16);
    }
    if (g == 0) {
        float sc = 1.f / fmaxf((float)dg, 1.f);
        const unsigned short* up = ub + (long)node * 64 + c16 * 16;
        uint4 u0 = *(const uint4*)up;
        uint4 u1 = *(const uint4*)(up + 8);
        float4 r0 = { a[0]*sc + bflo(u0.x), a[1]*sc + bfhi(u0.x),
                      a[2]*sc + bflo(u0.y), a[3]*sc + bfhi(u0.y) };
        float4 r1 = { a[4]*sc + bflo(u0.z), a[5]*sc + bfhi(u0.z),
                      a[6]*sc + bflo(u0.w), a[7]*sc + bfhi(u0.w) };
        float4 r2 = { a[8]*sc + bflo(u1.x), a[9]*sc + bfhi(u1.x),
                      a[10]*sc + bflo(u1.y), a[11]*sc + bfhi(u1.y) };
        float4 r3 = { a[12]*sc + bflo(u1.z), a[13]*sc + bfhi(u1.z),
                      a[14]*sc + bflo(u1.w), a[15]*sc + bfhi(u1.w) };
        float4* op = (float4*)(out + (long)node * 64 + c16 * 16);
        op[0] = r0; op[1] = r1; op[2] = r2; op[3] = r3;
    }
}

// ---- fused conv1 + conv2-transform, bf16 MFMA; t2 stored fp8, u stored bf16 ----
__global__ __launch_bounds__(256, 4) void fused_conv(
        const unsigned short* __restrict__ xb, const unsigned short* __restrict__ aggb,
        const unsigned short* __restrict__ w1, const float* __restrict__ bl1,
        const unsigned short* __restrict__ w2, const float* __restrict__ bl2,
        unsigned* __restrict__ t2q, unsigned short* __restrict__ ub) {
    __shared__ __align__(16) unsigned short smemA[64 * 136];
    __shared__ __align__(16) unsigned short smemH[64 * 136];
    unsigned short* sA = smemA;
    unsigned short* sH = smemH;
    unsigned short* stu = smemA;               // alias: u-stage [64][72] bf16
    unsigned char*  st2q = (unsigned char*)smemH;  // alias: t2-stage [64][80] fp8

    int t = threadIdx.x;
    int lane = t & 63;
    int wv = t >> 6;
    int q = lane >> 4, ln = lane & 15;

    long base = (long)blockIdx.x * 4096;
    long maxe = (long)N_NODES * 64 - 8;
#pragma unroll
    for (int it = 0; it < 2; it++) {
        int i = it * 256 + t;
        int m = i >> 3, k8 = (i & 7) * 8;
        long g = base + (long)m * 64 + k8;
        if (g > maxe) g = maxe;
        *(uint4*)(sA + m * 136 + k8)      = *(const uint4*)(aggb + g);
        *(uint4*)(sA + m * 136 + 64 + k8) = *(const uint4*)(xb + g);
    }
    __syncthreads();

    int n0 = wv * 32;
    float4v acc[2][4];
    {
        float b0 = bl1[n0 + ln], b1 = bl1[n0 + 16 + ln];
#pragma unroll
        for (int mi = 0; mi < 4; mi++) {
            acc[0][mi] = (float4v){b0, b0, b0, b0};
            acc[1][mi] = (float4v){b1, b1, b1, b1};
        }
    }
#pragma unroll
    for (int ks = 0; ks < 4; ks++) {
        int k0 = ks * 32 + q * 8;
        short8 bf0 = *(const short8*)(w1 + (long)(n0 + ln) * 128 + k0);
        short8 bf1 = *(const short8*)(w1 + (long)(n0 + 16 + ln) * 128 + k0);
#pragma unroll
        for (int mi = 0; mi < 4; mi++) {
            short8 af = *(const short8*)(sA + (mi * 16 + ln) * 136 + k0);
            acc[0][mi] = __builtin_amdgcn_mfma_f32_16x16x32_bf16(af, bf0, acc[0][mi], 0, 0, 0);
            acc[1][mi] = __builtin_amdgcn_mfma_f32_16x16x32_bf16(af, bf1, acc[1][mi], 0, 0, 0);
        }
    }
#pragma unroll
    for (int j = 0; j < 2; j++)
#pragma unroll
        for (int mi = 0; mi < 4; mi++) {
            int n = n0 + j * 16 + ln;
#pragma unroll
            for (int r = 0; r < 4; r++) {
                int m = mi * 16 + q * 4 + r;
                sH[m * 136 + n] = f2bf(fmaxf(acc[j][mi][r], 0.f));
            }
        }
    __syncthreads();

    float4v acc2[2][4];
    {
        float c0 = (n0 >= 64) ? bl2[n0 - 64 + ln] : 0.f;
        float c1 = (n0 >= 64) ? bl2[n0 - 48 + ln] : 0.f;
#pragma unroll
        for (int mi = 0; mi < 4; mi++) {
            acc2[0][mi] = (float4v){c0, c0, c0, c0};
            acc2[1][mi] = (float4v){c1, c1, c1, c1};
        }
    }
#pragma unroll
    for (int ks = 0; ks < 4; ks++) {
        int k0 = ks * 32 + q * 8;
        short8 bf0 = *(const short8*)(w2 + (long)(n0 + ln) * 128 + k0);
        short8 bf1 = *(const short8*)(w2 + (long)(n0 + 16 + ln) * 128 + k0);
#pragma unroll
        for (int mi = 0; mi < 4; mi++) {
            short8 af = *(const short8*)(sH + (mi * 16 + ln) * 136 + k0);
            acc2[0][mi] = __builtin_amdgcn_mfma_f32_16x16x32_bf16(af, bf0, acc2[0][mi], 0, 0, 0);
            acc2[1][mi] = __builtin_amdgcn_mfma_f32_16x16x32_bf16(af, bf1, acc2[1][mi], 0, 0, 0);
        }
    }
    __syncthreads();     // all reads of sA/sH done -> safe to alias stu/st2q

#pragma unroll
    for (int j = 0; j < 2; j++)
#pragma unroll
        for (int mi = 0; mi < 4; mi++) {
            int n = n0 + j * 16 + ln;
#pragma unroll
            for (int r = 0; r < 4; r++) {
                int m = mi * 16 + q * 4 + r;
                if (wv < 2) st2q[m * 80 + n] = f2fp8(acc2[j][mi][r]);
                else        stu[m * 72 + (n - 64)] = f2bf(acc2[j][mi][r]);
            }
        }
    __syncthreads();

    // t2q copy: 64 rows x 16 uints
    long qbase = (long)blockIdx.x * 1024;
    long qlim = (long)N_NODES * 16;
#pragma unroll
    for (int it = 0; it < 4; it++) {
        int i = it * 256 + t;
        long gq = qbase + i;
        if (gq < qlim) {
            int m = i >> 4, dw = i & 15;
            t2q[gq] = *(const unsigned*)(st2q + m * 80 + dw * 4);
        }
    }
    // u copy: 64 rows x 32 uints (2 bf16 each)
    long lim2 = (long)N_NODES * 32;
    unsigned* uu = (unsigned*)ub;
    long ubase = base >> 1;
#pragma unroll
    for (int it = 0; it < 8; it++) {
        int i = it * 256 + t;
        long gq = ubase + i;
        if (gq < lim2) {
            int m = (i * 2) >> 6, n = (i * 2) & 63;
            uu[gq] = (unsigned)stu[m * 72 + n] | ((unsigned)stu[m * 72 + n + 1] << 16);
        }
    }
}

// ---- fused classifier head, bf16 MFMA ----
__global__ __launch_bounds__(256, 4) void fused_cls(
        const float* __restrict__ emb,
        const unsigned short* __restrict__ wcls1, const float* __restrict__ bc1,
        const unsigned short* __restrict__ wcls2, const float* __restrict__ bc2,
        const float* __restrict__ wc3, const float* __restrict__ bc3,
        float* __restrict__ probs) {
    __shared__ __align__(16) unsigned short smem[64 * 136];
    __shared__ float psum[4][64];
    unsigned short* sE = smem;
    unsigned short* sC = smem;

    int t = threadIdx.x;
    int wv = t >> 6;
    int lane = t & 63;
    int q = lane >> 4, ln = lane & 15;

    long base = (long)blockIdx.x * 4096;
    long maxe = (long)N_NODES * 64 - 4;
#pragma unroll
    for (int it = 0; it < 4; it++) {
        int i = it * 256 + t;
        int m = i >> 4, k4 = (i & 15) * 4;
        long g = base + (long)m * 64 + k4;
        if (g > maxe) g = maxe;
        float4 v = *(const float4*)(emb + g);
        uint2 o;
        o.x = (unsigned)f2bf(v.x) | ((unsigned)f2bf(v.y) << 16);
        o.y = (unsigned)f2bf(v.z) | ((unsigned)f2bf(v.w) << 16);
        *(uint2*)(sE + m * 72 + k4) = o;
    }
    __syncthreads();

    int n0 = wv * 32;
    float4v acc[2][4];
    {
        float b0 = bc1[n0 + ln], b1 = bc1[n0 + 16 + ln];
#pragma unroll
        for (int mi = 0; mi < 4; mi++) {
            acc[0][mi] = (float4v){b0, b0, b0, b0};
            acc[1][mi] = (float4v){b1, b1, b1, b1};
        }
    }
#pragma unroll
    for (int ks = 0; ks < 2; ks++) {
        int k0 = ks * 32 + q * 8;
        short8 bf0 = *(const short8*)(wcls1 + (long)(n0 + ln) * 64 + k0);
        short8 bf1 = *(const short8*)(wcls1 + (long)(n0 + 16 + ln) * 64 + k0);
#pragma unroll
        for (int mi = 0; mi < 4; mi++) {
            short8 af = *(const short8*)(sE + (mi * 16 + ln) * 72 + k0);
            acc[0][mi] = __builtin_amdgcn_mfma_f32_16x16x32_bf16(af, bf0, acc[0][mi], 0, 0, 0);
            acc[1][mi] = __builtin_amdgcn_mfma_f32_16x16x32_bf16(af, bf1, acc[1][mi], 0, 0, 0);
        }
    }
    __syncthreads();
#pragma unroll
    for (int j = 0; j < 2; j++)
#pragma unroll
        for (int mi = 0; mi < 4; mi++) {
            int n = n0 + j * 16 + ln;
#pragma unroll
            for (int r = 0; r < 4; r++) {
                int m = mi * 16 + q * 4 + r;
                sC[m * 136 + n] = f2bf(fmaxf(acc[j][mi][r], 0.f));
            }
        }
    __syncthreads();

    int n0c = wv * 16;
    float4v acc3[4];
    {
        float b = bc2[n0c + ln];
#pragma unroll
        for (int mi = 0; mi < 4; mi++) acc3[mi] = (float4v){b, b, b, b};
    }
#pragma unroll
    for (int ks = 0; ks < 4; ks++) {
        int k0 = ks * 32 + q * 8;
        short8 bf0 = *(const short8*)(wcls2 + (long)(n0c + ln) * 128 + k0);
#pragma unroll
        for (int mi = 0; mi < 4; mi++) {
            short8 af = *(const short8*)(sC + (mi * 16 + ln) * 136 + k0);
            acc3[mi] = __builtin_amdgcn_mfma_f32_16x16x32_bf16(af, bf0, acc3[mi], 0, 0, 0);
        }
    }
    float w3 = wc3[n0c + ln];
#pragma unroll
    for (int mi = 0; mi < 4; mi++)
#pragma unroll
        for (int r = 0; r < 4; r++) {
            float v = fmaxf(acc3[mi][r], 0.f) * w3;
            v += __shfl_xor(v, 1);
            v += __shfl_xor(v, 2);
            v += __shfl_xor(v, 4);
            v += __shfl_xor(v, 8);
            if (ln == 0) psum[wv][mi * 16 + q * 4 + r] = v;
        }
    __syncthreads();
    if (t < 64) {
        int node = blockIdx.x * 64 + t;
        if (node < N_NODES) {
            float tot = psum[0][t] + psum[1][t] + psum[2][t] + psum[3][t] + bc3[0];
            probs[node] = 1.f / (1.f + expf(-tot));
        }
    }
}

extern "C" void kernel_launch(void* const* d_in, const int* in_sizes, int n_in,
                              void* d_out, int out_size, void* d_ws, size_t ws_size,
                              hipStream_t stream) {
    const float* x   = (const float*)d_in[0];
    const int*   ei  = (const int*)d_in[1];
    const float* Wl1 = (const float*)d_in[2];
    const float* bl1 = (const float*)d_in[3];
    const float* Wr1 = (const float*)d_in[4];
    const float* Wl2 = (const float*)d_in[5];
    const float* bl2 = (const float*)d_in[6];
    const float* Wr2 = (const float*)d_in[7];
    const float* Wc1 = (const float*)d_in[8];
    const float* bc1 = (const float*)d_in[9];
    const float* Wc2 = (const float*)d_in[10];
    const float* bc2 = (const float*)d_in[11];
    const float* Wc3 = (const float*)d_in[12];
    const float* bc3 = (const float*)d_in[13];

    float* out = (float*)d_out;

    // ---- ws carve (ints first) ----
    int* iw     = (int*)d_ws;
    int* bcnt   = iw;                       // 512 (zeroed)
    int* offp   = iw + 1024;                // 100352
    int* deg    = iw + 1024 + 100352;       // 100352
    int* bucket = iw + 1024 + 2 * 100352;   // BUCKET_CAP
    unsigned* stage = (unsigned*)(bucket + BUCKET_CAP);  // NBKT*BCAP
    size_t ioff = ((size_t)(1024 + 2 * 100352 + BUCKET_CAP) + (size_t)NBKT * BCAP) * 4;
    ioff = (ioff + 127) & ~(size_t)127;     // 128B align

    char* wsb = (char*)d_ws;
    unsigned short* xb    = (unsigned short*)(wsb + ioff);       // 100001 rows bf16
    unsigned short* agg1b = xb + 6400064L;                       // 100000 rows bf16
    unsigned short* ub    = agg1b + 6400000L;                    // 100000 rows bf16
    unsigned*       xq    = (unsigned*)(ub + 6400000L);          // 100001 rows fp8 (16 uints)
    unsigned*       t2q   = xq + 1600016L;                       // 100001 rows fp8
    unsigned short* w1    = (unsigned short*)(t2q + 1600016L);
    unsigned short* w2    = w1 + 16384;
    unsigned short* wcls1 = w2 + 16384;
    unsigned short* wcls2 = wcls1 + 8192;

    float* emb   = out;                     // [100000 x 64]
    float* probs = out + 6400000L;          // [100000]

    const int* esrc = ei;
    const int* edst = ei + N_EDGES;

    hipMemsetAsync(bcnt, 0, 1024 * sizeof(int), stream);

    prep_all<<<6443, 256, 0, stream>>>(x, xb, xq, Wl1, Wr1, Wl2, Wr2, Wc1, Wc2,
                                       w1, w2, wcls1, wcls2, t2q);

    binA<<<NBLKA, 256, 0, stream>>>(esrc, edst, bcnt, stage);
    binB<<<NBKT, 256, 0, stream>>>(bcnt, stage, offp, deg, bucket);

    gather_b<<<12500, 256, 0, stream>>>((const unsigned char*)xq, offp, deg, bucket, agg1b);
    fused_conv<<<1563, 256, 0, stream>>>(xb, agg1b, w1, bl1, w2, bl2, t2q, ub);
    gather_badd<<<12500, 256, 0, stream>>>((const unsigned char*)t2q, offp, deg, bucket, ub, emb);
    fused_cls<<<1563, 256, 0, stream>>>(emb, wcls1, bc1, wcls2, bc2, Wc3, bc3, probs);
}

// Round 15
// 243.593 us; speedup vs baseline: 1.7156x; 1.7156x over previous
//
#include <hip/hip_runtime.h>
#include <math.h>

#define N_NODES 100000
#define ZERO_NODE 100000        // sentinel row (zeroed) for neighbor-list padding
#define N_EDGES 1600000
#define NBKT    391             // ceil(100000/256) coarse buckets (256 nodes each)
#define BCAP    5120            // per-bucket capacity; mean 4092, +16 sigma
#define EPB     4096            // edges per binA block (16-entry reg stash, no spill)
#define NBLKA   391             // ceil(N_EDGES/EPB)
#define PADBKT  768             // max padding per bucket = 3*256 (pad to x4)
#define BUCKET_CAP (N_EDGES + NBKT * PADBKT + BCAP)   // + slack for clamped OOB reads

using short8  = __attribute__((ext_vector_type(8))) short;   // 8 bf16 (4 VGPRs)
using float4v = __attribute__((ext_vector_type(4))) float;   // MFMA C/D frag
using floatx2 = __attribute__((ext_vector_type(2))) float;

__device__ inline unsigned short f2bf(float f) {             // fp32 -> bf16 RNE
    unsigned int u = __float_as_uint(f);
    u += 0x7fffu + ((u >> 16) & 1u);
    return (unsigned short)(u >> 16);
}
__device__ inline float bflo(unsigned int v) { return __uint_as_float(v << 16); }
__device__ inline float bfhi(unsigned int v) { return __uint_as_float(v & 0xffff0000u); }
__device__ inline unsigned pk4fp8(float a, float b, float c, float d) {
    unsigned p = __builtin_amdgcn_cvt_pk_fp8_f32(a, b, 0, false);
    return __builtin_amdgcn_cvt_pk_fp8_f32(c, d, p, true);
}

// ---- prep: weights->bf16 [n][k]; x -> bf16 (xb) AND fp8 (xq); sentinel rows ----
__global__ void prep_all(const float* __restrict__ x, unsigned short* __restrict__ xb,
                         unsigned* __restrict__ xq,
                         const float* __restrict__ Wl1, const float* __restrict__ Wr1,
                         const float* __restrict__ Wl2, const float* __restrict__ Wr2,
                         const float* __restrict__ Wc1, const float* __restrict__ Wc2,
                         unsigned short* __restrict__ w1, unsigned short* __restrict__ w2,
                         unsigned short* __restrict__ wcls1, unsigned short* __restrict__ wcls2,
                         unsigned short* __restrict__ t2b) {
    int bid = blockIdx.x;
    int t = threadIdx.x;
    if (bid < 6250) {                                  // x conversion (4 ch / thread)
        int i = bid * 256 + t;
        float4 v = *(const float4*)(x + (long)i * 4);
        uint2 o;
        o.x = (unsigned)f2bf(v.x) | ((unsigned)f2bf(v.y) << 16);
        o.y = (unsigned)f2bf(v.z) | ((unsigned)f2bf(v.w) << 16);
        *(uint2*)(xb + (long)i * 4) = o;
        xq[i] = pk4fp8(v.x, v.y, v.z, v.w);
    } else if (bid < 6442) {                           // weights
        int i = (bid - 6250) * 256 + t;
        if (i < 16384) {
            int n = i >> 7, k = i & 127;
            float v = (k < 64) ? Wl1[k * 128 + n] : Wr1[(k - 64) * 128 + n];
            w1[i] = f2bf(v);
        } else if (i < 32768) {
            int j = i - 16384; int n = j >> 7, k = j & 127;
            float v = (n < 64) ? Wl2[k * 64 + n] : Wr2[k * 64 + (n - 64)];
            w2[j] = f2bf(v);
        } else if (i < 40960) {
            int j = i - 32768; int n = j >> 6, k = j & 63;
            wcls1[j] = f2bf(Wc1[k * 128 + n]);
        } else {
            int j = i - 40960; int n = j >> 7, k = j & 127;
            wcls2[j] = f2bf(Wc2[k * 64 + n]);
        }
    } else {                                           // zero sentinel rows
        if (t < 32)       ((unsigned*)(xb  + (long)ZERO_NODE * 64))[t]      = 0u;
        else if (t < 64)  ((unsigned*)(t2b + (long)ZERO_NODE * 64))[t - 32] = 0u;
        else if (t < 80)  xq[(long)ZERO_NODE * 16 + (t - 64)] = 0u;
    }
}

// ---- binned CSR build: phase A (16-entry register stash, no spill) ----
__global__ __launch_bounds__(256) void binA(const int* __restrict__ esrc,
                                            const int* __restrict__ edst,
                                            int* __restrict__ bcnt,
                                            unsigned* __restrict__ stage) {
    __shared__ int hist[NBKT];
    __shared__ int rbase[NBKT];
    int t = threadIdx.x;
    for (int i = t; i < NBKT; i += 256) hist[i] = 0;
    __syncthreads();
    int e0 = blockIdx.x * EPB;
    int e1 = e0 + EPB; if (e1 > N_EDGES) e1 = N_EDGES;
    unsigned pk[16];
    int bn[16];
#pragma unroll
    for (int j = 0; j < 16; j++) {
        int e = e0 + j * 256 + t;
        bn[j] = -1;
        if (e < N_EDGES && e < e1) {
            int d = edst[e];
            int s = esrc[e];
            int b = d >> 8;
            pk[j] = (unsigned)s | ((unsigned)(d & 255) << 24);
            bn[j] = b;
            atomicAdd(&hist[b], 1);
        }
    }
    __syncthreads();
    for (int i = t; i < NBKT; i += 256) {
        int c = hist[i];
        rbase[i] = c ? atomicAdd(&bcnt[i], c) : 0;
        hist[i] = 0;
    }
    __syncthreads();
#pragma unroll
    for (int j = 0; j < 16; j++) {
        if (bn[j] >= 0) {
            int b = bn[j];
            int slot = rbase[b] + atomicAdd(&hist[b], 1);
            if (slot < BCAP)
                stage[(long)b * BCAP + slot] = pk[j];
        }
    }
}

// Phase B: one block per bucket; self-scans bcnt; pad each node's list to x4.
__global__ __launch_bounds__(256) void binB(const int* __restrict__ bcnt,
                                            const unsigned* __restrict__ stage,
                                            int* __restrict__ offp, int* __restrict__ deg,
                                            int* __restrict__ bucket) {
    __shared__ int sg[512];
    __shared__ int hist[256];
    __shared__ int scn[256];
    __shared__ int lbase[256];
    int b = blockIdx.x, t = threadIdx.x;
    sg[t]       = (t < NBKT) ? bcnt[t] : 0;
    sg[t + 256] = (t + 256 < NBKT) ? bcnt[t + 256] : 0;
    hist[t] = 0;
    __syncthreads();
    for (int st = 1; st < 512; st <<= 1) {
        int a0 = (t >= st) ? sg[t - st] : 0;
        int a1 = (t + 256 >= st) ? sg[t + 256 - st] : 0;
        __syncthreads();
        sg[t] += a0; sg[t + 256] += a1;
        __syncthreads();
    }
    int cntraw = bcnt[b];
    int base = (sg[b] - cntraw) + b * PADBKT;
    int cnt = cntraw > BCAP ? BCAP : cntraw;
    const unsigned* sp = stage + (long)b * BCAP;
    unsigned pk[20];
    int nv = 0;
#pragma unroll
    for (int j = 0; j < 20; j++) {
        int i = j * 256 + t;
        if (i < cnt) {
            pk[j] = sp[i];
            atomicAdd(&hist[pk[j] >> 24], 1);
            nv = j + 1;
        }
    }
    __syncthreads();
    int v = hist[t];                       // true degree
    int p4 = (v + 3) & ~3;                 // padded x4
    scn[t] = p4;
    __syncthreads();
    for (int st = 1; st < 256; st <<= 1) {
        int a = (t >= st) ? scn[t - st] : 0;
        __syncthreads();
        scn[t] += a;
        __syncthreads();
    }
    lbase[t] = scn[t] - p4;
    int node = b * 256 + t;
    if (node < N_NODES) {
        offp[node] = base + lbase[t];
        deg[node]  = v;
    }
    hist[t] = 0;
    __syncthreads();
#pragma unroll
    for (int j = 0; j < 20; j++) {
        if (j < nv) {
            unsigned p = pk[j];
            int ln = p >> 24;
            int slot = atomicAdd(&hist[ln], 1);
            bucket[base + lbase[ln] + slot] = (int)(p & 0xFFFFFFu);
        }
    }
    int ps = base + lbase[t] + v;
    int pe = base + lbase[t] + p4;
    for (int j = ps; j < pe; j++) bucket[j] = ZERO_NODE;   // <=3 iters
}

// ---- fp8 x-gather: 2 nodes/wave. lane = (nh, slot g in [0,4), octet c8 in [0,8)) ----
// fp8 row = 64 B; each lane loads 8 B (uint2, 8 ch); a[8] accumulators -> no spill.
__global__ __launch_bounds__(256, 8) void gather_b(
        const unsigned char* __restrict__ yq, const int* __restrict__ offp,
        const int* __restrict__ deg, const int* __restrict__ bucket,
        unsigned short* __restrict__ outb) {
    int t = threadIdx.x;
    int wv = t >> 6, lane = t & 63;
    int nh = lane >> 5;
    int g  = (lane >> 3) & 3;
    int c8 = lane & 7;
    int node = blockIdx.x * 8 + wv * 2 + nh;       // 12500*8 = 100000 exact
    int e0 = offp[node];
    int dg = deg[node];
    int len = (dg + 3) & ~3;
    int other = __shfl_xor(len, 32);
    int maxlen = len > other ? len : other;
    float a[8] = {0.f, 0.f, 0.f, 0.f, 0.f, 0.f, 0.f, 0.f};
    for (int base = 0; base < maxlen; base += 16) {
        uint2 v[4];
#pragma unroll
        for (int h = 0; h < 4; h++) {
            int rel = base + h * 4 + g;
            int s = bucket[e0 + rel];
            s = (rel < len) ? s : ZERO_NODE;       // clamp BEFORE row load
            unsigned off = ((unsigned)s << 6) + ((unsigned)c8 << 3);
            v[h] = *(const uint2*)(yq + off);
        }
#pragma unroll
        for (int h = 0; h < 4; h++) {
            floatx2 d;
            d = __builtin_amdgcn_cvt_pk_f32_fp8(v[h].x, false); a[0] += d.x; a[1] += d.y;
            d = __builtin_amdgcn_cvt_pk_f32_fp8(v[h].x, true);  a[2] += d.x; a[3] += d.y;
            d = __builtin_amdgcn_cvt_pk_f32_fp8(v[h].y, false); a[4] += d.x; a[5] += d.y;
            d = __builtin_amdgcn_cvt_pk_f32_fp8(v[h].y, true);  a[6] += d.x; a[7] += d.y;
        }
    }
#pragma unroll
    for (int j = 0; j < 8; j++) {                  // reduce over g (lane bits 3,4)
        a[j] += __shfl_xor(a[j], 8);
        a[j] += __shfl_xor(a[j], 16);
    }
    if (g == 0) {                                  // 8 lanes/node, 8 bf16 ch each
        float sc = 1.f / fmaxf((float)dg, 1.f);
        uint4 o;
        o.x = (unsigned)f2bf(a[0]*sc) | ((unsigned)f2bf(a[1]*sc) << 16);
        o.y = (unsigned)f2bf(a[2]*sc) | ((unsigned)f2bf(a[3]*sc) << 16);
        o.z = (unsigned)f2bf(a[4]*sc) | ((unsigned)f2bf(a[5]*sc) << 16);
        o.w = (unsigned)f2bf(a[6]*sc) | ((unsigned)f2bf(a[7]*sc) << 16);
        *(uint4*)(outb + (long)node * 64 + c8 * 8) = o;
    }
}

// ---- bf16 t2-gather + bf16 u add, fp32 emb out (R13 version) ----
__global__ __launch_bounds__(256, 8) void gather_badd(
        const unsigned short* __restrict__ y, const int* __restrict__ offp,
        const int* __restrict__ deg, const int* __restrict__ bucket,
        const unsigned short* __restrict__ ub, float* __restrict__ out) {
    int t = threadIdx.x;
    int wv = t >> 6, lane = t & 63;
    int nh = lane >> 5;
    int g  = (lane >> 3) & 3;
    int c8 = lane & 7;
    int node = blockIdx.x * 8 + wv * 2 + nh;
    int e0 = offp[node];
    int dg = deg[node];
    int len = (dg + 3) & ~3;
    int other = __shfl_xor(len, 32);
    int maxlen = len > other ? len : other;
    const char* yb = (const char*)y;
    float a[8] = {0.f, 0.f, 0.f, 0.f, 0.f, 0.f, 0.f, 0.f};
    for (int base = 0; base < maxlen; base += 16) {
        uint4 v[4];
#pragma unroll
        for (int h = 0; h < 4; h++) {
            int rel = base + h * 4 + g;
            int s = bucket[e0 + rel];
            s = (rel < len) ? s : ZERO_NODE;
            unsigned off32 = ((unsigned)s << 7) + ((unsigned)c8 << 4);
            v[h] = *(const uint4*)(yb + off32);
        }
#pragma unroll
        for (int h = 0; h < 4; h++) {
            a[0] += bflo(v[h].x); a[1] += bfhi(v[h].x);
            a[2] += bflo(v[h].y); a[3] += bfhi(v[h].y);
            a[4] += bflo(v[h].z); a[5] += bfhi(v[h].z);
            a[6] += bflo(v[h].w); a[7] += bfhi(v[h].w);
        }
    }
#pragma unroll
    for (int j = 0; j < 8; j++) {
        a[j] += __shfl_xor(a[j], 8);
        a[j] += __shfl_xor(a[j], 16);
    }
    if (g == 0) {
        float sc = 1.f / fmaxf((float)dg, 1.f);
        uint2 uv = *(const uint2*)(ub + (long)node * 64 + c8 * 8);
        float4 r0 = { a[0]*sc + bflo(uv.x), a[1]*sc + bfhi(uv.x),
                      a[2]*sc + bflo(uv.y), a[3]*sc + bfhi(uv.y) };
        uint2 uw = *(const uint2*)(ub + (long)node * 64 + c8 * 8 + 4);
        float4 r1 = { a[4]*sc + bflo(uw.x), a[5]*sc + bfhi(uw.x),
                      a[6]*sc + bflo(uw.y), a[7]*sc + bfhi(uw.y) };
        float4* op = (float4*)(out + (long)node * 64 + c8 * 8);
        op[0] = r0; op[1] = r1;
    }
}

// ---- fused conv1 + conv2-transform, bf16 MFMA; t2/u staged+stored bf16 ----
__global__ __launch_bounds__(256, 4) void fused_conv(
        const unsigned short* __restrict__ xb, const unsigned short* __restrict__ aggb,
        const unsigned short* __restrict__ w1, const float* __restrict__ bl1,
        const unsigned short* __restrict__ w2, const float* __restrict__ bl2,
        unsigned short* __restrict__ t2b, unsigned short* __restrict__ ub) {
    __shared__ __align__(16) unsigned short smemA[64 * 136];
    __shared__ __align__(16) unsigned short smemH[64 * 136];
    unsigned short* sA = smemA;
    unsigned short* sH = smemH;
    unsigned short* stu = smemA;               // alias: u-stage [64][72] bf16
    unsigned short* st2 = smemH;               // alias: t2-stage [64][72] bf16

    int t = threadIdx.x;
    int lane = t & 63;
    int wv = t >> 6;
    int q = lane >> 4, ln = lane & 15;

    long base = (long)blockIdx.x * 4096;
    long maxe = (long)N_NODES * 64 - 8;
#pragma unroll
    for (int it = 0; it < 2; it++) {
        int i = it * 256 + t;
        int m = i >> 3, k8 = (i & 7) * 8;
        long g = base + (long)m * 64 + k8;
        if (g > maxe) g = maxe;
        *(uint4*)(sA + m * 136 + k8)      = *(const uint4*)(aggb + g);
        *(uint4*)(sA + m * 136 + 64 + k8) = *(const uint4*)(xb + g);
    }
    __syncthreads();

    int n0 = wv * 32;
    float4v acc[2][4];
    {
        float b0 = bl1[n0 + ln], b1 = bl1[n0 + 16 + ln];
#pragma unroll
        for (int mi = 0; mi < 4; mi++) {
            acc[0][mi] = (float4v){b0, b0, b0, b0};
            acc[1][mi] = (float4v){b1, b1, b1, b1};
        }
    }
#pragma unroll
    for (int ks = 0; ks < 4; ks++) {
        int k0 = ks * 32 + q * 8;
        short8 bf0 = *(const short8*)(w1 + (long)(n0 + ln) * 128 + k0);
        short8 bf1 = *(const short8*)(w1 + (long)(n0 + 16 + ln) * 128 + k0);
#pragma unroll
        for (int mi = 0; mi < 4; mi++) {
            short8 af = *(const short8*)(sA + (mi * 16 + ln) * 136 + k0);
            acc[0][mi] = __builtin_amdgcn_mfma_f32_16x16x32_bf16(af, bf0, acc[0][mi], 0, 0, 0);
            acc[1][mi] = __builtin_amdgcn_mfma_f32_16x16x32_bf16(af, bf1, acc[1][mi], 0, 0, 0);
        }
    }
#pragma unroll
    for (int j = 0; j < 2; j++)
#pragma unroll
        for (int mi = 0; mi < 4; mi++) {
            int n = n0 + j * 16 + ln;
#pragma unroll
            for (int r = 0; r < 4; r++) {
                int m = mi * 16 + q * 4 + r;
                sH[m * 136 + n] = f2bf(fmaxf(acc[j][mi][r], 0.f));
            }
        }
    __syncthreads();

    float4v acc2[2][4];
    {
        float c0 = (n0 >= 64) ? bl2[n0 - 64 + ln] : 0.f;
        float c1 = (n0 >= 64) ? bl2[n0 - 48 + ln] : 0.f;
#pragma unroll
        for (int mi = 0; mi < 4; mi++) {
            acc2[0][mi] = (float4v){c0, c0, c0, c0};
            acc2[1][mi] = (float4v){c1, c1, c1, c1};
        }
    }
#pragma unroll
    for (int ks = 0; ks < 4; ks++) {
        int k0 = ks * 32 + q * 8;
        short8 bf0 = *(const short8*)(w2 + (long)(n0 + ln) * 128 + k0);
        short8 bf1 = *(const short8*)(w2 + (long)(n0 + 16 + ln) * 128 + k0);
#pragma unroll
        for (int mi = 0; mi < 4; mi++) {
            short8 af = *(const short8*)(sH + (mi * 16 + ln) * 136 + k0);
            acc2[0][mi] = __builtin_amdgcn_mfma_f32_16x16x32_bf16(af, bf0, acc2[0][mi], 0, 0, 0);
            acc2[1][mi] = __builtin_amdgcn_mfma_f32_16x16x32_bf16(af, bf1, acc2[1][mi], 0, 0, 0);
        }
    }
    __syncthreads();     // all reads of sA/sH done

#pragma unroll
    for (int j = 0; j < 2; j++)
#pragma unroll
        for (int mi = 0; mi < 4; mi++) {
            int n = n0 + j * 16 + ln;
#pragma unroll
            for (int r = 0; r < 4; r++) {
                int m = mi * 16 + q * 4 + r;
                if (wv < 2) st2[m * 72 + n] = f2bf(acc2[j][mi][r]);
                else        stu[m * 72 + (n - 64)] = f2bf(acc2[j][mi][r]);
            }
        }
    __syncthreads();

    long lim2 = (long)N_NODES * 32;            // in uints (2 bf16 each)
    unsigned* t2u = (unsigned*)t2b;
    unsigned* uu  = (unsigned*)ub;
    long ubase = base >> 1;
#pragma unroll
    for (int it = 0; it < 8; it++) {
        int i = it * 256 + t;                  // uint index within tile (2048)
        long gq = ubase + i;
        if (gq < lim2) {
            int m = (i * 2) >> 6, n = (i * 2) & 63;
            t2u[gq] = (unsigned)st2[m * 72 + n] | ((unsigned)st2[m * 72 + n + 1] << 16);
            uu[gq]  = (unsigned)stu[m * 72 + n] | ((unsigned)stu[m * 72 + n + 1] << 16);
        }
    }
}

// ---- fused classifier head, bf16 MFMA ----
__global__ __launch_bounds__(256, 4) void fused_cls(
        const float* __restrict__ emb,
        const unsigned short* __restrict__ wcls1, const float* __restrict__ bc1,
        const unsigned short* __restrict__ wcls2, const float* __restrict__ bc2,
        const float* __restrict__ wc3, const float* __restrict__ bc3,
        float* __restrict__ probs) {
    __shared__ __align__(16) unsigned short smem[64 * 136];
    __shared__ float psum[4][64];
    unsigned short* sE = smem;
    unsigned short* sC = smem;

    int t = threadIdx.x;
    int wv = t >> 6;
    int lane = t & 63;
    int q = lane >> 4, ln = lane & 15;

    long base = (long)blockIdx.x * 4096;
    long maxe = (long)N_NODES * 64 - 4;
#pragma unroll
    for (int it = 0; it < 4; it++) {
        int i = it * 256 + t;
        int m = i >> 4, k4 = (i & 15) * 4;
        long g = base + (long)m * 64 + k4;
        if (g > maxe) g = maxe;
        float4 v = *(const float4*)(emb + g);
        uint2 o;
        o.x = (unsigned)f2bf(v.x) | ((unsigned)f2bf(v.y) << 16);
        o.y = (unsigned)f2bf(v.z) | ((unsigned)f2bf(v.w) << 16);
        *(uint2*)(sE + m * 72 + k4) = o;
    }
    __syncthreads();

    int n0 = wv * 32;
    float4v acc[2][4];
    {
        float b0 = bc1[n0 + ln], b1 = bc1[n0 + 16 + ln];
#pragma unroll
        for (int mi = 0; mi < 4; mi++) {
            acc[0][mi] = (float4v){b0, b0, b0, b0};
            acc[1][mi] = (float4v){b1, b1, b1, b1};
        }
    }
#pragma unroll
    for (int ks = 0; ks < 2; ks++) {
        int k0 = ks * 32 + q * 8;
        short8 bf0 = *(const short8*)(wcls1 + (long)(n0 + ln) * 64 + k0);
        short8 bf1 = *(const short8*)(wcls1 + (long)(n0 + 16 + ln) * 64 + k0);
#pragma unroll
        for (int mi = 0; mi < 4; mi++) {
            short8 af = *(const short8*)(sE + (mi * 16 + ln) * 72 + k0);
            acc[0][mi] = __builtin_amdgcn_mfma_f32_16x16x32_bf16(af, bf0, acc[0][mi], 0, 0, 0);
            acc[1][mi] = __builtin_amdgcn_mfma_f32_16x16x32_bf16(af, bf1, acc[1][mi], 0, 0, 0);
        }
    }
    __syncthreads();
#pragma unroll
    for (int j = 0; j < 2; j++)
#pragma unroll
        for (int mi = 0; mi < 4; mi++) {
            int n = n0 + j * 16 + ln;
#pragma unroll
            for (int r = 0; r < 4; r++) {
                int m = mi * 16 + q * 4 + r;
                sC[m * 136 + n] = f2bf(fmaxf(acc[j][mi][r], 0.f));
            }
        }
    __syncthreads();

    int n0c = wv * 16;
    float4v acc3[4];
    {
        float b = bc2[n0c + ln];
#pragma unroll
        for (int mi = 0; mi < 4; mi++) acc3[mi] = (float4v){b, b, b, b};
    }
#pragma unroll
    for (int ks = 0; ks < 4; ks++) {
        int k0 = ks * 32 + q * 8;
        short8 bf0 = *(const short8*)(wcls2 + (long)(n0c + ln) * 128 + k0);
#pragma unroll
        for (int mi = 0; mi < 4; mi++) {
            short8 af = *(const short8*)(sC + (mi * 16 + ln) * 136 + k0);
            acc3[mi] = __builtin_amdgcn_mfma_f32_16x16x32_bf16(af, bf0, acc3[mi], 0, 0, 0);
        }
    }
    float w3 = wc3[n0c + ln];
#pragma unroll
    for (int mi = 0; mi < 4; mi++)
#pragma unroll
        for (int r = 0; r < 4; r++) {
            float v = fmaxf(acc3[mi][r], 0.f) * w3;
            v += __shfl_xor(v, 1);
            v += __shfl_xor(v, 2);
            v += __shfl_xor(v, 4);
            v += __shfl_xor(v, 8);
            if (ln == 0) psum[wv][mi * 16 + q * 4 + r] = v;
        }
    __syncthreads();
    if (t < 64) {
        int node = blockIdx.x * 64 + t;
        if (node < N_NODES) {
            float tot = psum[0][t] + psum[1][t] + psum[2][t] + psum[3][t] + bc3[0];
            probs[node] = 1.f / (1.f + expf(-tot));
        }
    }
}

extern "C" void kernel_launch(void* const* d_in, const int* in_sizes, int n_in,
                              void* d_out, int out_size, void* d_ws, size_t ws_size,
                              hipStream_t stream) {
    const float* x   = (const float*)d_in[0];
    const int*   ei  = (const int*)d_in[1];
    const float* Wl1 = (const float*)d_in[2];
    const float* bl1 = (const float*)d_in[3];
    const float* Wr1 = (const float*)d_in[4];
    const float* Wl2 = (const float*)d_in[5];
    const float* bl2 = (const float*)d_in[6];
    const float* Wr2 = (const float*)d_in[7];
    const float* Wc1 = (const float*)d_in[8];
    const float* bc1 = (const float*)d_in[9];
    const float* Wc2 = (const float*)d_in[10];
    const float* bc2 = (const float*)d_in[11];
    const float* Wc3 = (const float*)d_in[12];
    const float* bc3 = (const float*)d_in[13];

    float* out = (float*)d_out;

    // ---- ws carve (ints first) ----
    int* iw     = (int*)d_ws;
    int* bcnt   = iw;                       // 512 (zeroed)
    int* offp   = iw + 1024;                // 100352
    int* deg    = iw + 1024 + 100352;       // 100352
    int* bucket = iw + 1024 + 2 * 100352;   // BUCKET_CAP
    unsigned* stage = (unsigned*)(bucket + BUCKET_CAP);  // NBKT*BCAP
    size_t ioff = ((size_t)(1024 + 2 * 100352 + BUCKET_CAP) + (size_t)NBKT * BCAP) * 4;
    ioff = (ioff + 127) & ~(size_t)127;     // 128B align

    char* wsb = (char*)d_ws;
    unsigned short* xb    = (unsigned short*)(wsb + ioff);       // 100001 rows bf16
    unsigned short* agg1b = xb + 6400064L;                       // 100000 rows bf16
    unsigned short* t2b   = agg1b + 6400000L;                    // 100001 rows bf16
    unsigned short* ub    = t2b + 6400064L;                      // 100000 rows bf16
    unsigned*       xq    = (unsigned*)(ub + 6400000L);          // 100001 rows fp8 (16 uints)
    unsigned short* w1    = (unsigned short*)(xq + 1600016L);
    unsigned short* w2    = w1 + 16384;
    unsigned short* wcls1 = w2 + 16384;
    unsigned short* wcls2 = wcls1 + 8192;

    float* emb   = out;                     // [100000 x 64]
    float* probs = out + 6400000L;          // [100000]

    const int* esrc = ei;
    const int* edst = ei + N_EDGES;

    hipMemsetAsync(bcnt, 0, 1024 * sizeof(int), stream);

    prep_all<<<6443, 256, 0, stream>>>(x, xb, xq, Wl1, Wr1, Wl2, Wr2, Wc1, Wc2,
                                       w1, w2, wcls1, wcls2, t2b);

    binA<<<NBLKA, 256, 0, stream>>>(esrc, edst, bcnt, stage);
    binB<<<NBKT, 256, 0, stream>>>(bcnt, stage, offp, deg, bucket);

    gather_b<<<12500, 256, 0, stream>>>((const unsigned char*)xq, offp, deg, bucket, agg1b);
    fused_conv<<<1563, 256, 0, stream>>>(xb, agg1b, w1, bl1, w2, bl2, t2b, ub);
    gather_badd<<<12500, 256, 0, stream>>>(t2b, offp, deg, bucket, ub, emb);
    fused_cls<<<1563, 256, 0, stream>>>(emb, wcls1, bc1, wcls2, bc2, Wc3, bc3, probs);
}